// Round 6
// baseline (718.779 us; speedup 1.0000x reference)
//
#include <hip/hip_runtime.h>
#include <hip/hip_bf16.h>
#include <cstdint>
#include <cstddef>

#define Tn 4096
#define Bn 64
#define Hn 256
#define En 256
#define Vn 50257
#define D2H 512   // 2H
#define K3H 768   // 3H

typedef __attribute__((ext_vector_type(8))) short short8;
typedef __attribute__((ext_vector_type(4))) float f32x4;

__device__ __forceinline__ short bfs(float f)
{
    __hip_bfloat16 h = __float2bfloat16(f);   // RNE
    return *reinterpret_cast<short*>(&h);
}

__device__ __forceinline__ short8 pack8(const float4 x0, const float4 x1)
{
    short8 r;
    r[0] = bfs(x0.x); r[1] = bfs(x0.y); r[2] = bfs(x0.z); r[3] = bfs(x0.w);
    r[4] = bfs(x1.x); r[5] = bfs(x1.y); r[6] = bfs(x1.z); r[7] = bfs(x1.w);
    return r;
}

// ---------------------------------------------------------------------------
// ws layout (float offsets):
//   baseT  : [0, 16384)          (256h x 64b)
//   emb_g  : [16384, 32768)      (64b x 256e)
//   attn   : [32768, 294912)     (4096t x 64b)
//   part   : [294912, 1343488)   (32tc x 64b x 512d)
//   y      : [1343488, 1392640)  (64b x 768)
//   w2frag : [1392640, 1458176)  256 KB bf16 W2 fragments
// ---------------------------------------------------------------------------

__global__ __launch_bounds__(256) void k1_embed_base(
    const int* __restrict__ ids, const float* __restrict__ hidden,
    const float* __restrict__ emb, const float* __restrict__ W_attn,
    const float* __restrict__ b_attn,
    float* __restrict__ baseT, float* __restrict__ emb_g)
{
    const int b = blockIdx.x, h = threadIdx.x;
    __shared__ float h0[Hn];
    h0[h] = hidden[b * Hn + h];
    __syncthreads();
    float acc = b_attn[h];
    const float* wrow = W_attn + (size_t)h * K3H;
#pragma unroll 8
    for (int k = 0; k < Hn; ++k) acc += wrow[k] * h0[k];
    baseT[h * Bn + b] = acc;
    const int id = ids[b];
    emb_g[b * En + h] = emb[(size_t)id * En + h];
}

// K1b: pack W2 into bf16 MFMA B-fragment layout.
__global__ __launch_bounds__(64) void k1b_w2frag(
    const float* __restrict__ W_attn, unsigned short* __restrict__ w2frag)
{
    const int blk = blockIdx.x;          // nt*16 + kb
    const int nt = blk >> 4, kb = blk & 15;
    const int l = threadIdx.x, lr = l & 15, lg = l >> 4;
    const int h = nt * 16 + lr;
    const float* src = W_attn + (size_t)h * K3H + Hn + kb * 32 + lg * 8;
    float4 x0 = *reinterpret_cast<const float4*>(src);
    float4 x1 = *reinterpret_cast<const float4*>(src + 4);
    reinterpret_cast<short8*>(w2frag)[(size_t)blk * 64 + l] = pack8(x0, x1);
}

// K2: MFMA GEMM. A staged via global_load_lds, LDS double buffer, read-side
// XOR swizzle with pre-swizzled global source (identical math to round 5).
// NEW: 1024 thr = 16 waves = 4 M-waves x 4 N-waves; acc[2][4] = 32 regs/thr
// (was 128) -> no spill, 4 waves/SIMD. M-tile 128, N 256, K-chunk 64.
__global__ __launch_bounds__(1024) void k2_scores(
    const float* __restrict__ enc, const unsigned short* __restrict__ w2frag,
    const float* __restrict__ vvec, const float* __restrict__ baseT,
    float* __restrict__ scores)
{
    const int tid = threadIdx.x;
    const int tb0 = blockIdx.x * 128;
    const int l = tid & 63;
    const int w = tid >> 6;            // 0..15
    const int mw = w >> 2, nwv = w & 3;
    const int lr = l & 15, lg = l >> 4;

    __shared__ float buf[2][8192];     // 2 x (128 rows x 64 f32) = 64 KB

    f32x4 acc[2][4];
    const f32x4 zero = {0.f, 0.f, 0.f, 0.f};
#pragma unroll
    for (int mi = 0; mi < 2; ++mi)
#pragma unroll
        for (int ni = 0; ni < 4; ++ni) acc[mi][ni] = zero;

    const short8* wf = reinterpret_cast<const short8*>(w2frag);

    // staging: wave w covers rows w*8 .. w*8+7, 2 issues of 4 rows each.
    // lane l -> row = w*8 + u*4 + lg, linear slot lr; global source fetches
    // logical slot (lr ^ (row&7)) so physical slot p holds logical p^(row&7).
    const float* gsrc = enc + (size_t)(tb0 + w * 8 + lg) * D2H;
    const int cs_even = ((lr ^ lg) << 2);          // u=0: row&7 = lg
    const int cs_odd  = ((lr ^ (lg + 4)) << 2);    // u=1: row&7 = lg+4

#define GLDS_CHUNK(kc, bsel) do {                                             \
    _Pragma("unroll")                                                         \
    for (int u = 0; u < 2; ++u) {                                             \
        const float* g = gsrc + (size_t)(u * 4) * D2H + (kc) * 64             \
                        + (u ? cs_odd : cs_even);                             \
        __builtin_amdgcn_global_load_lds(                                     \
            (const __attribute__((address_space(1))) void*)g,                 \
            (__attribute__((address_space(3))) void*)&buf[bsel][(w*8+u*4)*64],\
            16, 0, 0);                                                        \
    } } while (0)

#define COMPUTE_KB(bsel, kb, kb2) do {                                        \
    short8 bfr[4];                                                            \
    _Pragma("unroll")                                                         \
    for (int ni = 0; ni < 4; ++ni)                                            \
        bfr[ni] = wf[(size_t)(((nwv * 4 + ni) * 16) + (kb)) * 64 + l];        \
    const int s0 = (kb2) * 8 + lg * 2;                                        \
    const int o0 = (((s0    ) ^ (lr & 7)) << 2);                              \
    const int o1 = (((s0 + 1) ^ (lr & 7)) << 2);                              \
    _Pragma("unroll")                                                         \
    for (int mi = 0; mi < 2; ++mi) {                                          \
        const float* rb = &buf[bsel][(mw * 32 + mi * 16 + lr) * 64];          \
        float4 a0 = *reinterpret_cast<const float4*>(rb + o0);                \
        float4 a1 = *reinterpret_cast<const float4*>(rb + o1);                \
        short8 a = pack8(a0, a1);                                             \
        _Pragma("unroll")                                                     \
        for (int ni = 0; ni < 4; ++ni)                                        \
            acc[mi][ni] = __builtin_amdgcn_mfma_f32_16x16x32_bf16(            \
                a, bfr[ni], acc[mi][ni], 0, 0, 0);                            \
    } } while (0)

    // prologue: stage chunk 0
    GLDS_CHUNK(0, 0);
    __syncthreads();

    for (int kc = 0; kc < 8; ++kc) {
        const int cur = kc & 1;
        if (kc < 7) GLDS_CHUNK(kc + 1, cur ^ 1);
        COMPUTE_KB(cur, 2 * kc, 0);
        COMPUTE_KB(cur, 2 * kc + 1, 1);
        __syncthreads();               // drains prefetch; next buffer ready
    }
#undef GLDS_CHUNK
#undef COMPUTE_KB

    // epilogue: psum[mi][r] = sum_ni v[h]*tanh(acc + base)
    float psum[2][4];
#pragma unroll
    for (int mi = 0; mi < 2; ++mi)
#pragma unroll
        for (int r = 0; r < 4; ++r) psum[mi][r] = 0.f;
#pragma unroll
    for (int ni = 0; ni < 4; ++ni) {
        const int h = nwv * 64 + ni * 16 + lr;
        const float vh = vvec[h];
        const float* bt = baseT + h * Bn;
#pragma unroll
        for (int mi = 0; mi < 2; ++mi)
#pragma unroll
            for (int r = 0; r < 4; ++r) {
                const int bb = (mw * 32 + mi * 16 + lg * 4 + r) & 63;
                psum[mi][r] += vh * tanhf(acc[mi][ni][r] + bt[bb]);
            }
    }

    // cross-wave reduction over 64 cols (4 nwv x 16 lr), overlaid on buf
    float (*red)[65] = reinterpret_cast<float (*)[65]>(&buf[0][0]);
#pragma unroll
    for (int mi = 0; mi < 2; ++mi)
#pragma unroll
        for (int r = 0; r < 4; ++r)
            red[mw * 32 + mi * 16 + lg * 4 + r][nwv * 16 + lr] = psum[mi][r];
    __syncthreads();
    if (tid < 128) {
        float s = 0.f;
#pragma unroll
        for (int c = 0; c < 64; ++c) s += red[tid][c];
        scores[(size_t)tb0 + tid] = s;
    }
}

// K3: softmax over t for each b
__global__ __launch_bounds__(1024) void k3_softmax(float* __restrict__ sc)
{
    const int b = blockIdx.x;
    __shared__ float red[1024];
    float m = -1e30f;
    for (int t = threadIdx.x; t < Tn; t += 1024) m = fmaxf(m, sc[(size_t)t * Bn + b]);
    red[threadIdx.x] = m; __syncthreads();
    for (int s = 512; s > 0; s >>= 1) {
        if (threadIdx.x < s) red[threadIdx.x] = fmaxf(red[threadIdx.x], red[threadIdx.x + s]);
        __syncthreads();
    }
    m = red[0]; __syncthreads();
    float l = 0.f;
    for (int t = threadIdx.x; t < Tn; t += 1024) l += expf(sc[(size_t)t * Bn + b] - m);
    red[threadIdx.x] = l; __syncthreads();
    for (int s = 512; s > 0; s >>= 1) {
        if (threadIdx.x < s) red[threadIdx.x] += red[threadIdx.x + s];
        __syncthreads();
    }
    l = red[0];
    const float inv = 1.0f / l;
    for (int t = threadIdx.x; t < Tn; t += 1024) {
        size_t i = (size_t)t * Bn + b;
        sc[i] = expf(sc[i] - m) * inv;
    }
}

// K4: context partials, 8 independent accumulator streams
__global__ __launch_bounds__(256) void k4_ctx_part(
    const float* __restrict__ enc, const float* __restrict__ attn,
    float* __restrict__ part)
{
    const int tc = blockIdx.x, b = blockIdx.y, tid = threadIdx.x;
    const float* aw = attn + (size_t)tc * 128 * Bn + b;
    float2 s0 = {0.f,0.f}, s1 = {0.f,0.f}, s2 = {0.f,0.f}, s3 = {0.f,0.f};
    float2 s4 = {0.f,0.f}, s5 = {0.f,0.f}, s6 = {0.f,0.f}, s7 = {0.f,0.f};
#pragma unroll 2
    for (int tt = 0; tt < 128; tt += 8) {
        const float* e0 = enc + (size_t)(tc * 128 + tt) * (Bn * D2H) + b * D2H;
        const float w0 = aw[(tt + 0) * Bn];
        const float w1 = aw[(tt + 1) * Bn];
        const float w2 = aw[(tt + 2) * Bn];
        const float w3 = aw[(tt + 3) * Bn];
        const float w4 = aw[(tt + 4) * Bn];
        const float w5 = aw[(tt + 5) * Bn];
        const float w6 = aw[(tt + 6) * Bn];
        const float w7 = aw[(tt + 7) * Bn];
        const float2 v0 = reinterpret_cast<const float2*>(e0)[tid];
        const float2 v1 = reinterpret_cast<const float2*>(e0 + 1 * Bn * D2H)[tid];
        const float2 v2 = reinterpret_cast<const float2*>(e0 + 2 * Bn * D2H)[tid];
        const float2 v3 = reinterpret_cast<const float2*>(e0 + 3 * Bn * D2H)[tid];
        const float2 v4 = reinterpret_cast<const float2*>(e0 + 4 * Bn * D2H)[tid];
        const float2 v5 = reinterpret_cast<const float2*>(e0 + 5 * Bn * D2H)[tid];
        const float2 v6 = reinterpret_cast<const float2*>(e0 + 6 * Bn * D2H)[tid];
        const float2 v7 = reinterpret_cast<const float2*>(e0 + 7 * Bn * D2H)[tid];
        s0.x += w0 * v0.x; s0.y += w0 * v0.y;
        s1.x += w1 * v1.x; s1.y += w1 * v1.y;
        s2.x += w2 * v2.x; s2.y += w2 * v2.y;
        s3.x += w3 * v3.x; s3.y += w3 * v3.y;
        s4.x += w4 * v4.x; s4.y += w4 * v4.y;
        s5.x += w5 * v5.x; s5.y += w5 * v5.y;
        s6.x += w6 * v6.x; s6.y += w6 * v6.y;
        s7.x += w7 * v7.x; s7.y += w7 * v7.y;
    }
    float2 r;
    r.x = ((s0.x + s1.x) + (s2.x + s3.x)) + ((s4.x + s5.x) + (s6.x + s7.x));
    r.y = ((s0.y + s1.y) + (s2.y + s3.y)) + ((s4.y + s5.y) + (s6.y + s7.y));
    reinterpret_cast<float2*>(part + ((size_t)tc * Bn + b) * D2H)[tid] = r;
}

// K5: reduce partials -> ctx into y[b][256:768]
__global__ __launch_bounds__(256) void k5_ctx_reduce(
    const float* __restrict__ part, float* __restrict__ y)
{
    const int b = blockIdx.x, d = threadIdx.x;
    float c0 = 0.f, c1 = 0.f;
    for (int tc = 0; tc < 32; ++tc) {
        const float* p = part + ((size_t)tc * Bn + b) * D2H;
        c0 += p[d]; c1 += p[d + 256];
    }
    y[(size_t)b * K3H + Hn + d] = c0;
    y[(size_t)b * K3H + Hn + 256 + d] = c1;
}

// K6: combine + GRU
__global__ __launch_bounds__(256) void k6_gru(
    const float* __restrict__ hidden, const float* __restrict__ emb_g,
    const float* __restrict__ W_comb, const float* __restrict__ b_comb,
    const float* __restrict__ W_ih, const float* __restrict__ W_hh,
    const float* __restrict__ b_ih, const float* __restrict__ b_hh,
    float* __restrict__ y, float* __restrict__ out_hidden)
{
    const int b = blockIdx.x, h = threadIdx.x;
    __shared__ float in_[K3H];
    __shared__ float h0[Hn];
    __shared__ float comb[Hn];
    __shared__ float gx[K3H], gh[K3H];
    in_[h]       = y[(size_t)b * K3H + Hn + h];
    in_[256 + h] = y[(size_t)b * K3H + Hn + 256 + h];
    in_[512 + h] = emb_g[b * En + h];
    h0[h] = hidden[b * Hn + h];
    __syncthreads();
    {
        float c = b_comb[h];
        const float* wr = W_comb + (size_t)h * K3H;
#pragma unroll 8
        for (int k = 0; k < K3H; ++k) c += wr[k] * in_[k];
        comb[h] = c;
    }
    __syncthreads();
#pragma unroll
    for (int p = 0; p < 3; ++p) {
        const int g = p * 256 + h;
        float a = b_ih[g], bh = b_hh[g];
        const float* wi = W_ih + (size_t)g * Hn;
        const float* wh = W_hh + (size_t)g * Hn;
#pragma unroll 8
        for (int k = 0; k < Hn; ++k) { a += wi[k] * comb[k]; bh += wh[k] * h0[k]; }
        gx[g] = a; gh[g] = bh;
    }
    __syncthreads();
    const float r = 1.f / (1.f + expf(-(gx[h] + gh[h])));
    const float z = 1.f / (1.f + expf(-(gx[256 + h] + gh[256 + h])));
    const float n = tanhf(gx[512 + h] + r * gh[512 + h]);
    const float hn = (1.f - z) * n + z * h0[h];
    y[(size_t)b * K3H + h] = hn;
    out_hidden[b * Hn + h] = hn;
}

// K7: logits GEMM (64v x 64b tiles)
__global__ __launch_bounds__(256) void k7_logits(
    const float* __restrict__ W_out, const float* __restrict__ b_out,
    const float* __restrict__ y, float* __restrict__ out)
{
    const int vbase = blockIdx.x * 64;
    const int tv = threadIdx.x & 15;
    const int tb = threadIdx.x >> 4;
    __shared__ float lw[64][33];
    __shared__ float ly[32][68];
    float acc[4][4] = {};
    for (int kc = 0; kc < 24; ++kc) {
        __syncthreads();
#pragma unroll
        for (int u = 0; u < 8; ++u) {
            int idx = threadIdx.x + u * 256;
            int r = idx >> 5, c = idx & 31;
            int vv = vbase + r;
            lw[r][c] = (vv < Vn) ? W_out[(size_t)vv * K3H + kc * 32 + c] : 0.f;
        }
#pragma unroll
        for (int u = 0; u < 8; ++u) {
            int idx = threadIdx.x + u * 256;
            int k = idx >> 6, bb = idx & 63;
            ly[k][bb] = y[(size_t)bb * K3H + kc * 32 + k];
        }
        __syncthreads();
        for (int k = 0; k < 32; ++k) {
            float wv[4], yv[4];
#pragma unroll
            for (int i = 0; i < 4; ++i) wv[i] = lw[tv * 4 + i][k];
#pragma unroll
            for (int j = 0; j < 4; ++j) yv[j] = ly[k][tb * 4 + j];
#pragma unroll
            for (int i = 0; i < 4; ++i)
#pragma unroll
                for (int j = 0; j < 4; ++j) acc[i][j] += wv[i] * yv[j];
        }
    }
#pragma unroll
    for (int i = 0; i < 4; ++i) {
        const int vv = vbase + tv * 4 + i;
        if (vv < Vn) {
            const float bo = b_out[vv];
#pragma unroll
            for (int j = 0; j < 4; ++j) {
                const int b = tb * 4 + j;
                out[(size_t)b * Vn + vv] = acc[i][j] + bo;
            }
        }
    }
}

// K8: log_softmax over V per row
__global__ __launch_bounds__(1024) void k8_logsoftmax(float* __restrict__ out)
{
    const int b = blockIdx.x;
    float* row = out + (size_t)b * Vn;
    __shared__ float red[1024];
    float m = -1e30f;
    for (int i = threadIdx.x; i < Vn; i += 1024) m = fmaxf(m, row[i]);
    red[threadIdx.x] = m; __syncthreads();
    for (int s = 512; s > 0; s >>= 1) {
        if (threadIdx.x < s) red[threadIdx.x] = fmaxf(red[threadIdx.x], red[threadIdx.x + s]);
        __syncthreads();
    }
    m = red[0]; __syncthreads();
    float l = 0.f;
    for (int i = threadIdx.x; i < Vn; i += 1024) l += expf(row[i] - m);
    red[threadIdx.x] = l; __syncthreads();
    for (int s = 512; s > 0; s >>= 1) {
        if (threadIdx.x < s) red[threadIdx.x] += red[threadIdx.x + s];
        __syncthreads();
    }
    l = red[0];
    const float off = m + logf(l);
    for (int i = threadIdx.x; i < Vn; i += 1024) row[i] = row[i] - off;
}

extern "C" void kernel_launch(void* const* d_in, const int* in_sizes, int n_in,
                              void* d_out, int out_size, void* d_ws, size_t ws_size,
                              hipStream_t stream)
{
    const int*   ids    = (const int*)d_in[0];
    const float* hidden = (const float*)d_in[1];
    const float* enc    = (const float*)d_in[2];
    const float* emb    = (const float*)d_in[3];
    const float* W_attn = (const float*)d_in[4];
    const float* b_attn = (const float*)d_in[5];
    const float* vvec   = (const float*)d_in[6];
    const float* W_comb = (const float*)d_in[7];
    const float* b_comb = (const float*)d_in[8];
    const float* W_ih   = (const float*)d_in[9];
    const float* W_hh   = (const float*)d_in[10];
    const float* b_ih   = (const float*)d_in[11];
    const float* b_hh   = (const float*)d_in[12];
    const float* W_out  = (const float*)d_in[13];
    const float* b_out  = (const float*)d_in[14];

    float* out = (float*)d_out;
    float* ws = (float*)d_ws;
    float* baseT = ws;                        // 16384
    float* emb_g = ws + 16384;                // 16384
    float* attn  = ws + 32768;                // 262144
    float* part  = ws + 294912;               // 1048576
    float* y     = ws + 1343488;              // 49152
    unsigned short* w2frag = (unsigned short*)(ws + 1392640); // 131072 bf16

    hipLaunchKernelGGL(k1_embed_base, dim3(Bn), dim3(256), 0, stream,
                       ids, hidden, emb, W_attn, b_attn, baseT, emb_g);
    hipLaunchKernelGGL(k1b_w2frag, dim3(256), dim3(64), 0, stream,
                       W_attn, w2frag);
    hipLaunchKernelGGL(k2_scores, dim3(2048), dim3(1024), 0, stream,
                       enc, w2frag, vvec, baseT, attn);
    hipLaunchKernelGGL(k3_softmax, dim3(Bn), dim3(1024), 0, stream, attn);
    hipLaunchKernelGGL(k4_ctx_part, dim3(32, Bn), dim3(256), 0, stream,
                       enc, attn, part);
    hipLaunchKernelGGL(k5_ctx_reduce, dim3(Bn), dim3(256), 0, stream, part, y);
    hipLaunchKernelGGL(k6_gru, dim3(Bn), dim3(256), 0, stream,
                       hidden, emb_g, W_comb, b_comb, W_ih, W_hh, b_ih, b_hh,
                       y, out + (size_t)Bn * Vn);
    hipLaunchKernelGGL(k7_logits, dim3((Vn + 63) / 64), dim3(256), 0, stream,
                       W_out, b_out, y, out);
    hipLaunchKernelGGL(k8_logsoftmax, dim3(Bn), dim3(1024), 0, stream, out);
}

// Round 7
// 686.754 us; speedup vs baseline: 1.0466x; 1.0466x over previous
//
#include <hip/hip_runtime.h>
#include <hip/hip_bf16.h>
#include <cstdint>
#include <cstddef>

#define Tn 4096
#define Bn 64
#define Hn 256
#define En 256
#define Vn 50257
#define D2H 512   // 2H
#define K3H 768   // 3H

typedef __attribute__((ext_vector_type(8))) short short8;
typedef __attribute__((ext_vector_type(4))) float f32x4;

__device__ __forceinline__ short bfs(float f)
{
    __hip_bfloat16 h = __float2bfloat16(f);   // RNE
    return *reinterpret_cast<short*>(&h);
}

__device__ __forceinline__ short8 pack8(const float4 x0, const float4 x1)
{
    short8 r;
    r[0] = bfs(x0.x); r[1] = bfs(x0.y); r[2] = bfs(x0.z); r[3] = bfs(x0.w);
    r[4] = bfs(x1.x); r[5] = bfs(x1.y); r[6] = bfs(x1.z); r[7] = bfs(x1.w);
    return r;
}

// ---------------------------------------------------------------------------
// ws layout (float offsets):
//   baseT  : [0, 16384)          (256h x 64b)
//   emb_g  : [16384, 32768)      (64b x 256e)
//   attn   : [32768, 294912)     (4096t x 64b)
//   part   : [294912, 1343488)   (32tc x 64b x 512d)
//   y      : [1343488, 1392640)  (64b x 768)
//   w2frag : [1392640, 1458176)  256 KB bf16 W2 fragments
// ---------------------------------------------------------------------------

__global__ __launch_bounds__(256) void k1_embed_base(
    const int* __restrict__ ids, const float* __restrict__ hidden,
    const float* __restrict__ emb, const float* __restrict__ W_attn,
    const float* __restrict__ b_attn,
    float* __restrict__ baseT, float* __restrict__ emb_g)
{
    const int b = blockIdx.x, h = threadIdx.x;
    __shared__ float h0[Hn];
    h0[h] = hidden[b * Hn + h];
    __syncthreads();
    float acc = b_attn[h];
    const float* wrow = W_attn + (size_t)h * K3H;
#pragma unroll 8
    for (int k = 0; k < Hn; ++k) acc += wrow[k] * h0[k];
    baseT[h * Bn + b] = acc;
    const int id = ids[b];
    emb_g[b * En + h] = emb[(size_t)id * En + h];
}

// K1b: pack W2 into bf16 MFMA B-fragment layout.
__global__ __launch_bounds__(64) void k1b_w2frag(
    const float* __restrict__ W_attn, unsigned short* __restrict__ w2frag)
{
    const int blk = blockIdx.x;          // nt*16 + kb
    const int nt = blk >> 4, kb = blk & 15;
    const int l = threadIdx.x, lr = l & 15, lg = l >> 4;
    const int h = nt * 16 + lr;
    const float* src = W_attn + (size_t)h * K3H + Hn + kb * 32 + lg * 8;
    float4 x0 = *reinterpret_cast<const float4*>(src);
    float4 x1 = *reinterpret_cast<const float4*>(src + 4);
    reinterpret_cast<short8*>(w2frag)[(size_t)blk * 64 + l] = pack8(x0, x1);
}

// K2: MFMA GEMM. A staged via global_load_lds, LDS double buffer, read-side
// XOR swizzle with pre-swizzled global source (same math as rounds 5/6).
// NEW: 256 thr = 4 waves = 1 M-group x 4 N-waves; M-tile 64, acc[4][4]=64
// regs; LDS 2x16 KB -> 4 blocks/CU = 4 independent barrier domains (m114
// overlap); zero intra-block B-duplication.
__global__ __launch_bounds__(256, 4) void k2_scores(
    const float* __restrict__ enc, const unsigned short* __restrict__ w2frag,
    const float* __restrict__ vvec, const float* __restrict__ baseT,
    float* __restrict__ scores)
{
    const int tid = threadIdx.x;
    const int tb0 = blockIdx.x * 64;
    const int l = tid & 63;
    const int w = tid >> 6;            // 0..3 = nwv (N-slice of 64 h)
    const int lr = l & 15, lg = l >> 4;

    __shared__ float buf[2][4096];     // 2 x (64 rows x 64 f32) = 32 KB

    f32x4 acc[4][4];
    const f32x4 zero = {0.f, 0.f, 0.f, 0.f};
#pragma unroll
    for (int mi = 0; mi < 4; ++mi)
#pragma unroll
        for (int ni = 0; ni < 4; ++ni) acc[mi][ni] = zero;

    const short8* wf = reinterpret_cast<const short8*>(w2frag);

    // staging: wave w covers rows w*16 .. w*16+15, 4 issues of 4 rows each.
    // lane l -> row = w*16 + u*4 + lg, linear slot lr; global source fetches
    // logical slot (lr ^ (row&7)) so physical slot p holds logical p^(row&7).
    const float* gsrc = enc + (size_t)(tb0 + w * 16 + lg) * D2H;
    const int cs_even = ((lr ^ lg) << 2);          // u even: row&7 = lg
    const int cs_odd  = ((lr ^ (lg + 4)) << 2);    // u odd : row&7 = lg+4

#define GLDS_CHUNK(kc, bsel) do {                                             \
    _Pragma("unroll")                                                         \
    for (int u = 0; u < 4; ++u) {                                             \
        const float* g = gsrc + (size_t)(u * 4) * D2H + (kc) * 64             \
                        + ((u & 1) ? cs_odd : cs_even);                       \
        __builtin_amdgcn_global_load_lds(                                     \
            (const __attribute__((address_space(1))) void*)g,                 \
            (__attribute__((address_space(3))) void*)                         \
                &buf[bsel][(w * 16 + u * 4) * 64],                            \
            16, 0, 0);                                                        \
    } } while (0)

#define COMPUTE_KB(bsel, kb, kb2) do {                                        \
    short8 bfr[4];                                                            \
    _Pragma("unroll")                                                         \
    for (int ni = 0; ni < 4; ++ni)                                            \
        bfr[ni] = wf[(size_t)(((w * 4 + ni) * 16) + (kb)) * 64 + l];          \
    const int s0 = (kb2) * 8 + lg * 2;                                        \
    const int o0 = (((s0    ) ^ (lr & 7)) << 2);                              \
    const int o1 = (((s0 + 1) ^ (lr & 7)) << 2);                              \
    _Pragma("unroll")                                                         \
    for (int mi = 0; mi < 4; ++mi) {                                          \
        const float* rb = &buf[bsel][(mi * 16 + lr) * 64];                    \
        float4 a0 = *reinterpret_cast<const float4*>(rb + o0);                \
        float4 a1 = *reinterpret_cast<const float4*>(rb + o1);                \
        short8 a = pack8(a0, a1);                                             \
        _Pragma("unroll")                                                     \
        for (int ni = 0; ni < 4; ++ni)                                        \
            acc[mi][ni] = __builtin_amdgcn_mfma_f32_16x16x32_bf16(            \
                a, bfr[ni], acc[mi][ni], 0, 0, 0);                            \
    } } while (0)

    // prologue: stage chunk 0
    GLDS_CHUNK(0, 0);
    __syncthreads();

    for (int kc = 0; kc < 8; ++kc) {
        const int cur = kc & 1;
        if (kc < 7) GLDS_CHUNK(kc + 1, cur ^ 1);
        COMPUTE_KB(cur, 2 * kc, 0);
        COMPUTE_KB(cur, 2 * kc + 1, 1);
        __syncthreads();               // drains prefetch; next buffer ready
    }
#undef GLDS_CHUNK
#undef COMPUTE_KB

    // epilogue: psum[mi][r] = sum_ni v[h]*tanh(acc + base); row = mi*16+lg*4+r
    float psum[4][4];
#pragma unroll
    for (int mi = 0; mi < 4; ++mi)
#pragma unroll
        for (int r = 0; r < 4; ++r) psum[mi][r] = 0.f;
#pragma unroll
    for (int ni = 0; ni < 4; ++ni) {
        const int h = w * 64 + ni * 16 + lr;
        const float vh = vvec[h];
        const float* bt = baseT + h * Bn;
#pragma unroll
        for (int mi = 0; mi < 4; ++mi)
#pragma unroll
            for (int r = 0; r < 4; ++r) {
                const int row = mi * 16 + lg * 4 + r;   // = b (tb0 mult of 64)
                psum[mi][r] += vh * tanhf(acc[mi][ni][r] + bt[row]);
            }
    }

    // cross-wave reduction: red[64 rows][64 cols = w*16+lr], overlaid on buf
    float (*red)[65] = reinterpret_cast<float (*)[65]>(&buf[0][0]);
#pragma unroll
    for (int mi = 0; mi < 4; ++mi)
#pragma unroll
        for (int r = 0; r < 4; ++r)
            red[mi * 16 + lg * 4 + r][w * 16 + lr] = psum[mi][r];
    __syncthreads();
    if (tid < 64) {
        float s = 0.f;
#pragma unroll
        for (int c = 0; c < 64; ++c) s += red[tid][c];
        scores[(size_t)tb0 + tid] = s;
    }
}

// K3: softmax over t for each b
__global__ __launch_bounds__(1024) void k3_softmax(float* __restrict__ sc)
{
    const int b = blockIdx.x;
    __shared__ float red[1024];
    float m = -1e30f;
    for (int t = threadIdx.x; t < Tn; t += 1024) m = fmaxf(m, sc[(size_t)t * Bn + b]);
    red[threadIdx.x] = m; __syncthreads();
    for (int s = 512; s > 0; s >>= 1) {
        if (threadIdx.x < s) red[threadIdx.x] = fmaxf(red[threadIdx.x], red[threadIdx.x + s]);
        __syncthreads();
    }
    m = red[0]; __syncthreads();
    float l = 0.f;
    for (int t = threadIdx.x; t < Tn; t += 1024) l += expf(sc[(size_t)t * Bn + b] - m);
    red[threadIdx.x] = l; __syncthreads();
    for (int s = 512; s > 0; s >>= 1) {
        if (threadIdx.x < s) red[threadIdx.x] += red[threadIdx.x + s];
        __syncthreads();
    }
    l = red[0];
    const float inv = 1.0f / l;
    for (int t = threadIdx.x; t < Tn; t += 1024) {
        size_t i = (size_t)t * Bn + b;
        sc[i] = expf(sc[i] - m) * inv;
    }
}

// K4: context partials, 8 independent accumulator streams
__global__ __launch_bounds__(256) void k4_ctx_part(
    const float* __restrict__ enc, const float* __restrict__ attn,
    float* __restrict__ part)
{
    const int tc = blockIdx.x, b = blockIdx.y, tid = threadIdx.x;
    const float* aw = attn + (size_t)tc * 128 * Bn + b;
    float2 s0 = {0.f,0.f}, s1 = {0.f,0.f}, s2 = {0.f,0.f}, s3 = {0.f,0.f};
    float2 s4 = {0.f,0.f}, s5 = {0.f,0.f}, s6 = {0.f,0.f}, s7 = {0.f,0.f};
#pragma unroll 2
    for (int tt = 0; tt < 128; tt += 8) {
        const float* e0 = enc + (size_t)(tc * 128 + tt) * (Bn * D2H) + b * D2H;
        const float w0 = aw[(tt + 0) * Bn];
        const float w1 = aw[(tt + 1) * Bn];
        const float w2 = aw[(tt + 2) * Bn];
        const float w3 = aw[(tt + 3) * Bn];
        const float w4 = aw[(tt + 4) * Bn];
        const float w5 = aw[(tt + 5) * Bn];
        const float w6 = aw[(tt + 6) * Bn];
        const float w7 = aw[(tt + 7) * Bn];
        const float2 v0 = reinterpret_cast<const float2*>(e0)[tid];
        const float2 v1 = reinterpret_cast<const float2*>(e0 + 1 * Bn * D2H)[tid];
        const float2 v2 = reinterpret_cast<const float2*>(e0 + 2 * Bn * D2H)[tid];
        const float2 v3 = reinterpret_cast<const float2*>(e0 + 3 * Bn * D2H)[tid];
        const float2 v4 = reinterpret_cast<const float2*>(e0 + 4 * Bn * D2H)[tid];
        const float2 v5 = reinterpret_cast<const float2*>(e0 + 5 * Bn * D2H)[tid];
        const float2 v6 = reinterpret_cast<const float2*>(e0 + 6 * Bn * D2H)[tid];
        const float2 v7 = reinterpret_cast<const float2*>(e0 + 7 * Bn * D2H)[tid];
        s0.x += w0 * v0.x; s0.y += w0 * v0.y;
        s1.x += w1 * v1.x; s1.y += w1 * v1.y;
        s2.x += w2 * v2.x; s2.y += w2 * v2.y;
        s3.x += w3 * v3.x; s3.y += w3 * v3.y;
        s4.x += w4 * v4.x; s4.y += w4 * v4.y;
        s5.x += w5 * v5.x; s5.y += w5 * v5.y;
        s6.x += w6 * v6.x; s6.y += w6 * v6.y;
        s7.x += w7 * v7.x; s7.y += w7 * v7.y;
    }
    float2 r;
    r.x = ((s0.x + s1.x) + (s2.x + s3.x)) + ((s4.x + s5.x) + (s6.x + s7.x));
    r.y = ((s0.y + s1.y) + (s2.y + s3.y)) + ((s4.y + s5.y) + (s6.y + s7.y));
    reinterpret_cast<float2*>(part + ((size_t)tc * Bn + b) * D2H)[tid] = r;
}

// K5: reduce partials -> ctx into y[b][256:768]
__global__ __launch_bounds__(256) void k5_ctx_reduce(
    const float* __restrict__ part, float* __restrict__ y)
{
    const int b = blockIdx.x, d = threadIdx.x;
    float c0 = 0.f, c1 = 0.f;
    for (int tc = 0; tc < 32; ++tc) {
        const float* p = part + ((size_t)tc * Bn + b) * D2H;
        c0 += p[d]; c1 += p[d + 256];
    }
    y[(size_t)b * K3H + Hn + d] = c0;
    y[(size_t)b * K3H + Hn + 256 + d] = c1;
}

// K6: combine + GRU
__global__ __launch_bounds__(256) void k6_gru(
    const float* __restrict__ hidden, const float* __restrict__ emb_g,
    const float* __restrict__ W_comb, const float* __restrict__ b_comb,
    const float* __restrict__ W_ih, const float* __restrict__ W_hh,
    const float* __restrict__ b_ih, const float* __restrict__ b_hh,
    float* __restrict__ y, float* __restrict__ out_hidden)
{
    const int b = blockIdx.x, h = threadIdx.x;
    __shared__ float in_[K3H];
    __shared__ float h0[Hn];
    __shared__ float comb[Hn];
    __shared__ float gx[K3H], gh[K3H];
    in_[h]       = y[(size_t)b * K3H + Hn + h];
    in_[256 + h] = y[(size_t)b * K3H + Hn + 256 + h];
    in_[512 + h] = emb_g[b * En + h];
    h0[h] = hidden[b * Hn + h];
    __syncthreads();
    {
        float c = b_comb[h];
        const float* wr = W_comb + (size_t)h * K3H;
#pragma unroll 8
        for (int k = 0; k < K3H; ++k) c += wr[k] * in_[k];
        comb[h] = c;
    }
    __syncthreads();
#pragma unroll
    for (int p = 0; p < 3; ++p) {
        const int g = p * 256 + h;
        float a = b_ih[g], bh = b_hh[g];
        const float* wi = W_ih + (size_t)g * Hn;
        const float* wh = W_hh + (size_t)g * Hn;
#pragma unroll 8
        for (int k = 0; k < Hn; ++k) { a += wi[k] * comb[k]; bh += wh[k] * h0[k]; }
        gx[g] = a; gh[g] = bh;
    }
    __syncthreads();
    const float r = 1.f / (1.f + expf(-(gx[h] + gh[h])));
    const float z = 1.f / (1.f + expf(-(gx[256 + h] + gh[256 + h])));
    const float n = tanhf(gx[512 + h] + r * gh[512 + h]);
    const float hn = (1.f - z) * n + z * h0[h];
    y[(size_t)b * K3H + h] = hn;
    out_hidden[b * Hn + h] = hn;
}

// K7: logits GEMM (64v x 64b tiles)
__global__ __launch_bounds__(256) void k7_logits(
    const float* __restrict__ W_out, const float* __restrict__ b_out,
    const float* __restrict__ y, float* __restrict__ out)
{
    const int vbase = blockIdx.x * 64;
    const int tv = threadIdx.x & 15;
    const int tb = threadIdx.x >> 4;
    __shared__ float lw[64][33];
    __shared__ float ly[32][68];
    float acc[4][4] = {};
    for (int kc = 0; kc < 24; ++kc) {
        __syncthreads();
#pragma unroll
        for (int u = 0; u < 8; ++u) {
            int idx = threadIdx.x + u * 256;
            int r = idx >> 5, c = idx & 31;
            int vv = vbase + r;
            lw[r][c] = (vv < Vn) ? W_out[(size_t)vv * K3H + kc * 32 + c] : 0.f;
        }
#pragma unroll
        for (int u = 0; u < 8; ++u) {
            int idx = threadIdx.x + u * 256;
            int k = idx >> 6, bb = idx & 63;
            ly[k][bb] = y[(size_t)bb * K3H + kc * 32 + k];
        }
        __syncthreads();
        for (int k = 0; k < 32; ++k) {
            float wv[4], yv[4];
#pragma unroll
            for (int i = 0; i < 4; ++i) wv[i] = lw[tv * 4 + i][k];
#pragma unroll
            for (int j = 0; j < 4; ++j) yv[j] = ly[k][tb * 4 + j];
#pragma unroll
            for (int i = 0; i < 4; ++i)
#pragma unroll
                for (int j = 0; j < 4; ++j) acc[i][j] += wv[i] * yv[j];
        }
    }
#pragma unroll
    for (int i = 0; i < 4; ++i) {
        const int vv = vbase + tv * 4 + i;
        if (vv < Vn) {
            const float bo = b_out[vv];
#pragma unroll
            for (int j = 0; j < 4; ++j) {
                const int b = tb * 4 + j;
                out[(size_t)b * Vn + vv] = acc[i][j] + bo;
            }
        }
    }
}

// K8: log_softmax over V per row
__global__ __launch_bounds__(1024) void k8_logsoftmax(float* __restrict__ out)
{
    const int b = blockIdx.x;
    float* row = out + (size_t)b * Vn;
    __shared__ float red[1024];
    float m = -1e30f;
    for (int i = threadIdx.x; i < Vn; i += 1024) m = fmaxf(m, row[i]);
    red[threadIdx.x] = m; __syncthreads();
    for (int s = 512; s > 0; s >>= 1) {
        if (threadIdx.x < s) red[threadIdx.x] = fmaxf(red[threadIdx.x], red[threadIdx.x + s]);
        __syncthreads();
    }
    m = red[0]; __syncthreads();
    float l = 0.f;
    for (int i = threadIdx.x; i < Vn; i += 1024) l += expf(row[i] - m);
    red[threadIdx.x] = l; __syncthreads();
    for (int s = 512; s > 0; s >>= 1) {
        if (threadIdx.x < s) red[threadIdx.x] += red[threadIdx.x + s];
        __syncthreads();
    }
    l = red[0];
    const float off = m + logf(l);
    for (int i = threadIdx.x; i < Vn; i += 1024) row[i] = row[i] - off;
}

extern "C" void kernel_launch(void* const* d_in, const int* in_sizes, int n_in,
                              void* d_out, int out_size, void* d_ws, size_t ws_size,
                              hipStream_t stream)
{
    const int*   ids    = (const int*)d_in[0];
    const float* hidden = (const float*)d_in[1];
    const float* enc    = (const float*)d_in[2];
    const float* emb    = (const float*)d_in[3];
    const float* W_attn = (const float*)d_in[4];
    const float* b_attn = (const float*)d_in[5];
    const float* vvec   = (const float*)d_in[6];
    const float* W_comb = (const float*)d_in[7];
    const float* b_comb = (const float*)d_in[8];
    const float* W_ih   = (const float*)d_in[9];
    const float* W_hh   = (const float*)d_in[10];
    const float* b_ih   = (const float*)d_in[11];
    const float* b_hh   = (const float*)d_in[12];
    const float* W_out  = (const float*)d_in[13];
    const float* b_out  = (const float*)d_in[14];

    float* out = (float*)d_out;
    float* ws = (float*)d_ws;
    float* baseT = ws;                        // 16384
    float* emb_g = ws + 16384;                // 16384
    float* attn  = ws + 32768;                // 262144
    float* part  = ws + 294912;               // 1048576
    float* y     = ws + 1343488;              // 49152
    unsigned short* w2frag = (unsigned short*)(ws + 1392640); // 131072 bf16

    hipLaunchKernelGGL(k1_embed_base, dim3(Bn), dim3(256), 0, stream,
                       ids, hidden, emb, W_attn, b_attn, baseT, emb_g);
    hipLaunchKernelGGL(k1b_w2frag, dim3(256), dim3(64), 0, stream,
                       W_attn, w2frag);
    hipLaunchKernelGGL(k2_scores, dim3(4096), dim3(256), 0, stream,
                       enc, w2frag, vvec, baseT, attn);
    hipLaunchKernelGGL(k3_softmax, dim3(Bn), dim3(1024), 0, stream, attn);
    hipLaunchKernelGGL(k4_ctx_part, dim3(32, Bn), dim3(256), 0, stream,
                       enc, attn, part);
    hipLaunchKernelGGL(k5_ctx_reduce, dim3(Bn), dim3(256), 0, stream, part, y);
    hipLaunchKernelGGL(k6_gru, dim3(Bn), dim3(256), 0, stream,
                       hidden, emb_g, W_comb, b_comb, W_ih, W_hh, b_ih, b_hh,
                       y, out + (size_t)Bn * Vn);
    hipLaunchKernelGGL(k7_logits, dim3((Vn + 63) / 64), dim3(256), 0, stream,
                       W_out, b_out, y, out);
    hipLaunchKernelGGL(k8_logsoftmax, dim3(Bn), dim3(1024), 0, stream, out);
}

// Round 8
// 666.615 us; speedup vs baseline: 1.0783x; 1.0302x over previous
//
#include <hip/hip_runtime.h>
#include <hip/hip_bf16.h>
#include <cstdint>
#include <cstddef>

#define Tn 4096
#define Bn 64
#define Hn 256
#define En 256
#define Vn 50257
#define D2H 512   // 2H
#define K3H 768   // 3H

typedef __attribute__((ext_vector_type(8))) short short8;
typedef __attribute__((ext_vector_type(4))) float f32x4;

__device__ __forceinline__ short bfs(float f)
{
    __hip_bfloat16 h = __float2bfloat16(f);   // RNE
    return *reinterpret_cast<short*>(&h);
}

__device__ __forceinline__ short8 pack8(const float4 x0, const float4 x1)
{
    short8 r;
    r[0] = bfs(x0.x); r[1] = bfs(x0.y); r[2] = bfs(x0.z); r[3] = bfs(x0.w);
    r[4] = bfs(x1.x); r[5] = bfs(x1.y); r[6] = bfs(x1.z); r[7] = bfs(x1.w);
    return r;
}

// ---------------------------------------------------------------------------
// ws layout (float offsets):
//   baseT  : [0, 16384)          (256h x 64b)
//   emb_g  : [16384, 32768)      (64b x 256e)
//   attn   : [32768, 294912)     (4096t x 64b)
//   part   : [294912, 1343488)   (32tc x 64b x 512d)
//   y      : [1343488, 1392640)  (64b x 768)
//   w2frag : [1392640, 1458176)  256 KB bf16 W2 fragments
// ---------------------------------------------------------------------------

__global__ __launch_bounds__(256) void k1_embed_base(
    const int* __restrict__ ids, const float* __restrict__ hidden,
    const float* __restrict__ emb, const float* __restrict__ W_attn,
    const float* __restrict__ b_attn,
    float* __restrict__ baseT, float* __restrict__ emb_g)
{
    const int b = blockIdx.x, h = threadIdx.x;
    __shared__ float h0[Hn];
    h0[h] = hidden[b * Hn + h];
    __syncthreads();
    float acc = b_attn[h];
    const float* wrow = W_attn + (size_t)h * K3H;
#pragma unroll 8
    for (int k = 0; k < Hn; ++k) acc += wrow[k] * h0[k];
    baseT[h * Bn + b] = acc;
    const int id = ids[b];
    emb_g[b * En + h] = emb[(size_t)id * En + h];
}

// K1b: pack W2 into bf16 MFMA B-fragment layout.
__global__ __launch_bounds__(64) void k1b_w2frag(
    const float* __restrict__ W_attn, unsigned short* __restrict__ w2frag)
{
    const int blk = blockIdx.x;          // nt*16 + kb
    const int nt = blk >> 4, kb = blk & 15;
    const int l = threadIdx.x, lr = l & 15, lg = l >> 4;
    const int h = nt * 16 + lr;
    const float* src = W_attn + (size_t)h * K3H + Hn + kb * 32 + lg * 8;
    float4 x0 = *reinterpret_cast<const float4*>(src);
    float4 x1 = *reinterpret_cast<const float4*>(src + 4);
    reinterpret_cast<short8*>(w2frag)[(size_t)blk * 64 + l] = pack8(x0, x1);
}

// K2: MFMA GEMM. A staged via global_load_lds into TRIPLE-buffered LDS,
// prefetch distance 2, counted-vmcnt barriers (loads stay in flight across
// s_barrier, 8-phase-template discipline). bfr (B-frag) loads issued BEFORE
// the chunk's gloads so the compiler's bfr-wait does not drain the HBM
// prefetch (vmcnt retires in FIFO order). Same fragment/swizzle math as the
// passing rounds 5-7.
__global__ __launch_bounds__(256, 3) void k2_scores(
    const float* __restrict__ enc, const unsigned short* __restrict__ w2frag,
    const float* __restrict__ vvec, const float* __restrict__ baseT,
    float* __restrict__ scores)
{
    const int tid = threadIdx.x;
    const int tb0 = blockIdx.x * 64;
    const int l = tid & 63;
    const int w = tid >> 6;            // 0..3 = N-slice of 64 h
    const int lr = l & 15, lg = l >> 4;

    __shared__ float buf[3][4096];     // 3 x (64 rows x 64 f32) = 48 KB

    f32x4 acc[4][4];
    const f32x4 zero = {0.f, 0.f, 0.f, 0.f};
#pragma unroll
    for (int mi = 0; mi < 4; ++mi)
#pragma unroll
        for (int ni = 0; ni < 4; ++ni) acc[mi][ni] = zero;

    const short8* wf = reinterpret_cast<const short8*>(w2frag);

    // staging: wave w covers rows w*16 .. w*16+15, 4 issues of 4 rows each.
    // lane l -> row = w*16 + u*4 + lg, linear slot lr; global source fetches
    // logical slot (lr ^ (row&7)) so physical slot p holds logical p^(row&7).
    const float* gsrc = enc + (size_t)(tb0 + w * 16 + lg) * D2H;
    const int cs_even = ((lr ^ lg) << 2);          // u even: row&7 = lg
    const int cs_odd  = ((lr ^ (lg + 4)) << 2);    // u odd : row&7 = lg+4

#define GLDS_CHUNK(kc, bsel) do {                                             \
    _Pragma("unroll")                                                         \
    for (int u = 0; u < 4; ++u) {                                             \
        const float* g = gsrc + (size_t)(u * 4) * D2H + (kc) * 64             \
                        + ((u & 1) ? cs_odd : cs_even);                       \
        __builtin_amdgcn_global_load_lds(                                     \
            (const __attribute__((address_space(1))) void*)g,                 \
            (__attribute__((address_space(3))) void*)                         \
                &buf[bsel][(w * 16 + u * 4) * 64],                            \
            16, 0, 0);                                                        \
    } } while (0)

#define COMPUTE_KB(bsel, kb2, bfr) do {                                       \
    const int s0 = (kb2) * 8 + lg * 2;                                        \
    const int o0 = (((s0    ) ^ (lr & 7)) << 2);                              \
    const int o1 = (((s0 + 1) ^ (lr & 7)) << 2);                              \
    _Pragma("unroll")                                                         \
    for (int mi = 0; mi < 4; ++mi) {                                          \
        const float* rb = &buf[bsel][(mi * 16 + lr) * 64];                    \
        float4 a0 = *reinterpret_cast<const float4*>(rb + o0);                \
        float4 a1 = *reinterpret_cast<const float4*>(rb + o1);                \
        short8 a = pack8(a0, a1);                                             \
        _Pragma("unroll")                                                     \
        for (int ni = 0; ni < 4; ++ni)                                        \
            acc[mi][ni] = __builtin_amdgcn_mfma_f32_16x16x32_bf16(            \
                a, bfr[ni], acc[mi][ni], 0, 0, 0);                            \
    } } while (0)

    // prologue: stage chunks 0 and 1 (depth-2 pipeline fill)
    GLDS_CHUNK(0, 0);
    GLDS_CHUNK(1, 1);
    // wait chunk-0 gloads only (chunk-1's 4 stay in flight across barrier)
    asm volatile("s_waitcnt vmcnt(4)" ::: "memory");
    __builtin_amdgcn_s_barrier();
    __builtin_amdgcn_sched_barrier(0);

#pragma unroll
    for (int kc = 0; kc < 8; ++kc) {
        const int cur = kc % 3;
        // B-fragments for both K-halves FIRST (FIFO: their wait does not
        // drain the gloads issued after them)
        short8 bfr0[4], bfr1[4];
#pragma unroll
        for (int ni = 0; ni < 4; ++ni)
            bfr0[ni] = wf[(size_t)(((w * 4 + ni) * 16) + 2 * kc) * 64 + l];
#pragma unroll
        for (int ni = 0; ni < 4; ++ni)
            bfr1[ni] = wf[(size_t)(((w * 4 + ni) * 16) + 2 * kc + 1) * 64 + l];
        if (kc < 6) GLDS_CHUNK(kc + 2, (kc + 2) % 3);

        COMPUTE_KB(cur, 0, bfr0);
        COMPUTE_KB(cur, 1, bfr1);

        // end of chunk: this chunk's 4 gloads may stay in flight across the
        // barrier; everything older (incl. next chunk's buffer) must retire.
        if (kc < 6) asm volatile("s_waitcnt vmcnt(4)" ::: "memory");
        else        asm volatile("s_waitcnt vmcnt(0)" ::: "memory");
        asm volatile("s_waitcnt lgkmcnt(0)" ::: "memory");
        __builtin_amdgcn_s_barrier();
        __builtin_amdgcn_sched_barrier(0);
    }
#undef GLDS_CHUNK
#undef COMPUTE_KB

    // epilogue: psum[mi][r] = sum_ni v[h]*tanh(acc + base); row = mi*16+lg*4+r
    float psum[4][4];
#pragma unroll
    for (int mi = 0; mi < 4; ++mi)
#pragma unroll
        for (int r = 0; r < 4; ++r) psum[mi][r] = 0.f;
#pragma unroll
    for (int ni = 0; ni < 4; ++ni) {
        const int h = w * 64 + ni * 16 + lr;
        const float vh = vvec[h];
        const float* bt = baseT + h * Bn;
#pragma unroll
        for (int mi = 0; mi < 4; ++mi)
#pragma unroll
            for (int r = 0; r < 4; ++r) {
                const int row = mi * 16 + lg * 4 + r;   // = b (tb0 mult of 64)
                psum[mi][r] += vh * tanhf(acc[mi][ni][r] + bt[row]);
            }
    }

    // cross-wave reduction: red[64 rows][64 cols = w*16+lr], overlaid on buf
    float (*red)[65] = reinterpret_cast<float (*)[65]>(&buf[0][0]);
#pragma unroll
    for (int mi = 0; mi < 4; ++mi)
#pragma unroll
        for (int r = 0; r < 4; ++r)
            red[mi * 16 + lg * 4 + r][w * 16 + lr] = psum[mi][r];
    __syncthreads();
    if (tid < 64) {
        float s = 0.f;
#pragma unroll
        for (int c = 0; c < 64; ++c) s += red[tid][c];
        scores[(size_t)tb0 + tid] = s;
    }
}

// K3: softmax over t for each b
__global__ __launch_bounds__(1024) void k3_softmax(float* __restrict__ sc)
{
    const int b = blockIdx.x;
    __shared__ float red[1024];
    float m = -1e30f;
    for (int t = threadIdx.x; t < Tn; t += 1024) m = fmaxf(m, sc[(size_t)t * Bn + b]);
    red[threadIdx.x] = m; __syncthreads();
    for (int s = 512; s > 0; s >>= 1) {
        if (threadIdx.x < s) red[threadIdx.x] = fmaxf(red[threadIdx.x], red[threadIdx.x + s]);
        __syncthreads();
    }
    m = red[0]; __syncthreads();
    float l = 0.f;
    for (int t = threadIdx.x; t < Tn; t += 1024) l += expf(sc[(size_t)t * Bn + b] - m);
    red[threadIdx.x] = l; __syncthreads();
    for (int s = 512; s > 0; s >>= 1) {
        if (threadIdx.x < s) red[threadIdx.x] += red[threadIdx.x + s];
        __syncthreads();
    }
    l = red[0];
    const float inv = 1.0f / l;
    for (int t = threadIdx.x; t < Tn; t += 1024) {
        size_t i = (size_t)t * Bn + b;
        sc[i] = expf(sc[i] - m) * inv;
    }
}

// K4: context partials, 8 independent accumulator streams
__global__ __launch_bounds__(256) void k4_ctx_part(
    const float* __restrict__ enc, const float* __restrict__ attn,
    float* __restrict__ part)
{
    const int tc = blockIdx.x, b = blockIdx.y, tid = threadIdx.x;
    const float* aw = attn + (size_t)tc * 128 * Bn + b;
    float2 s0 = {0.f,0.f}, s1 = {0.f,0.f}, s2 = {0.f,0.f}, s3 = {0.f,0.f};
    float2 s4 = {0.f,0.f}, s5 = {0.f,0.f}, s6 = {0.f,0.f}, s7 = {0.f,0.f};
#pragma unroll 2
    for (int tt = 0; tt < 128; tt += 8) {
        const float* e0 = enc + (size_t)(tc * 128 + tt) * (Bn * D2H) + b * D2H;
        const float w0 = aw[(tt + 0) * Bn];
        const float w1 = aw[(tt + 1) * Bn];
        const float w2 = aw[(tt + 2) * Bn];
        const float w3 = aw[(tt + 3) * Bn];
        const float w4 = aw[(tt + 4) * Bn];
        const float w5 = aw[(tt + 5) * Bn];
        const float w6 = aw[(tt + 6) * Bn];
        const float w7 = aw[(tt + 7) * Bn];
        const float2 v0 = reinterpret_cast<const float2*>(e0)[tid];
        const float2 v1 = reinterpret_cast<const float2*>(e0 + 1 * Bn * D2H)[tid];
        const float2 v2 = reinterpret_cast<const float2*>(e0 + 2 * Bn * D2H)[tid];
        const float2 v3 = reinterpret_cast<const float2*>(e0 + 3 * Bn * D2H)[tid];
        const float2 v4 = reinterpret_cast<const float2*>(e0 + 4 * Bn * D2H)[tid];
        const float2 v5 = reinterpret_cast<const float2*>(e0 + 5 * Bn * D2H)[tid];
        const float2 v6 = reinterpret_cast<const float2*>(e0 + 6 * Bn * D2H)[tid];
        const float2 v7 = reinterpret_cast<const float2*>(e0 + 7 * Bn * D2H)[tid];
        s0.x += w0 * v0.x; s0.y += w0 * v0.y;
        s1.x += w1 * v1.x; s1.y += w1 * v1.y;
        s2.x += w2 * v2.x; s2.y += w2 * v2.y;
        s3.x += w3 * v3.x; s3.y += w3 * v3.y;
        s4.x += w4 * v4.x; s4.y += w4 * v4.y;
        s5.x += w5 * v5.x; s5.y += w5 * v5.y;
        s6.x += w6 * v6.x; s6.y += w6 * v6.y;
        s7.x += w7 * v7.x; s7.y += w7 * v7.y;
    }
    float2 r;
    r.x = ((s0.x + s1.x) + (s2.x + s3.x)) + ((s4.x + s5.x) + (s6.x + s7.x));
    r.y = ((s0.y + s1.y) + (s2.y + s3.y)) + ((s4.y + s5.y) + (s6.y + s7.y));
    reinterpret_cast<float2*>(part + ((size_t)tc * Bn + b) * D2H)[tid] = r;
}

// K5: reduce partials -> ctx into y[b][256:768]
__global__ __launch_bounds__(256) void k5_ctx_reduce(
    const float* __restrict__ part, float* __restrict__ y)
{
    const int b = blockIdx.x, d = threadIdx.x;
    float c0 = 0.f, c1 = 0.f;
    for (int tc = 0; tc < 32; ++tc) {
        const float* p = part + ((size_t)tc * Bn + b) * D2H;
        c0 += p[d]; c1 += p[d + 256];
    }
    y[(size_t)b * K3H + Hn + d] = c0;
    y[(size_t)b * K3H + Hn + 256 + d] = c1;
}

// K6: combine + GRU
__global__ __launch_bounds__(256) void k6_gru(
    const float* __restrict__ hidden, const float* __restrict__ emb_g,
    const float* __restrict__ W_comb, const float* __restrict__ b_comb,
    const float* __restrict__ W_ih, const float* __restrict__ W_hh,
    const float* __restrict__ b_ih, const float* __restrict__ b_hh,
    float* __restrict__ y, float* __restrict__ out_hidden)
{
    const int b = blockIdx.x, h = threadIdx.x;
    __shared__ float in_[K3H];
    __shared__ float h0[Hn];
    __shared__ float comb[Hn];
    __shared__ float gx[K3H], gh[K3H];
    in_[h]       = y[(size_t)b * K3H + Hn + h];
    in_[256 + h] = y[(size_t)b * K3H + Hn + 256 + h];
    in_[512 + h] = emb_g[b * En + h];
    h0[h] = hidden[b * Hn + h];
    __syncthreads();
    {
        float c = b_comb[h];
        const float* wr = W_comb + (size_t)h * K3H;
#pragma unroll 8
        for (int k = 0; k < K3H; ++k) c += wr[k] * in_[k];
        comb[h] = c;
    }
    __syncthreads();
#pragma unroll
    for (int p = 0; p < 3; ++p) {
        const int g = p * 256 + h;
        float a = b_ih[g], bh = b_hh[g];
        const float* wi = W_ih + (size_t)g * Hn;
        const float* wh = W_hh + (size_t)g * Hn;
#pragma unroll 8
        for (int k = 0; k < Hn; ++k) { a += wi[k] * comb[k]; bh += wh[k] * h0[k]; }
        gx[g] = a; gh[g] = bh;
    }
    __syncthreads();
    const float r = 1.f / (1.f + expf(-(gx[h] + gh[h])));
    const float z = 1.f / (1.f + expf(-(gx[256 + h] + gh[256 + h])));
    const float n = tanhf(gx[512 + h] + r * gh[512 + h]);
    const float hn = (1.f - z) * n + z * h0[h];
    y[(size_t)b * K3H + h] = hn;
    out_hidden[b * Hn + h] = hn;
}

// K7: logits GEMM (64v x 64b tiles)
__global__ __launch_bounds__(256) void k7_logits(
    const float* __restrict__ W_out, const float* __restrict__ b_out,
    const float* __restrict__ y, float* __restrict__ out)
{
    const int vbase = blockIdx.x * 64;
    const int tv = threadIdx.x & 15;
    const int tb = threadIdx.x >> 4;
    __shared__ float lw[64][33];
    __shared__ float ly[32][68];
    float acc[4][4] = {};
    for (int kc = 0; kc < 24; ++kc) {
        __syncthreads();
#pragma unroll
        for (int u = 0; u < 8; ++u) {
            int idx = threadIdx.x + u * 256;
            int r = idx >> 5, c = idx & 31;
            int vv = vbase + r;
            lw[r][c] = (vv < Vn) ? W_out[(size_t)vv * K3H + kc * 32 + c] : 0.f;
        }
#pragma unroll
        for (int u = 0; u < 8; ++u) {
            int idx = threadIdx.x + u * 256;
            int k = idx >> 6, bb = idx & 63;
            ly[k][bb] = y[(size_t)bb * K3H + kc * 32 + k];
        }
        __syncthreads();
        for (int k = 0; k < 32; ++k) {
            float wv[4], yv[4];
#pragma unroll
            for (int i = 0; i < 4; ++i) wv[i] = lw[tv * 4 + i][k];
#pragma unroll
            for (int j = 0; j < 4; ++j) yv[j] = ly[k][tb * 4 + j];
#pragma unroll
            for (int i = 0; i < 4; ++i)
#pragma unroll
                for (int j = 0; j < 4; ++j) acc[i][j] += wv[i] * yv[j];
        }
    }
#pragma unroll
    for (int i = 0; i < 4; ++i) {
        const int vv = vbase + tv * 4 + i;
        if (vv < Vn) {
            const float bo = b_out[vv];
#pragma unroll
            for (int j = 0; j < 4; ++j) {
                const int b = tb * 4 + j;
                out[(size_t)b * Vn + vv] = acc[i][j] + bo;
            }
        }
    }
}

// K8: log_softmax over V per row
__global__ __launch_bounds__(1024) void k8_logsoftmax(float* __restrict__ out)
{
    const int b = blockIdx.x;
    float* row = out + (size_t)b * Vn;
    __shared__ float red[1024];
    float m = -1e30f;
    for (int i = threadIdx.x; i < Vn; i += 1024) m = fmaxf(m, row[i]);
    red[threadIdx.x] = m; __syncthreads();
    for (int s = 512; s > 0; s >>= 1) {
        if (threadIdx.x < s) red[threadIdx.x] = fmaxf(red[threadIdx.x], red[threadIdx.x + s]);
        __syncthreads();
    }
    m = red[0]; __syncthreads();
    float l = 0.f;
    for (int i = threadIdx.x; i < Vn; i += 1024) l += expf(row[i] - m);
    red[threadIdx.x] = l; __syncthreads();
    for (int s = 512; s > 0; s >>= 1) {
        if (threadIdx.x < s) red[threadIdx.x] += red[threadIdx.x + s];
        __syncthreads();
    }
    l = red[0];
    const float off = m + logf(l);
    for (int i = threadIdx.x; i < Vn; i += 1024) row[i] = row[i] - off;
}

extern "C" void kernel_launch(void* const* d_in, const int* in_sizes, int n_in,
                              void* d_out, int out_size, void* d_ws, size_t ws_size,
                              hipStream_t stream)
{
    const int*   ids    = (const int*)d_in[0];
    const float* hidden = (const float*)d_in[1];
    const float* enc    = (const float*)d_in[2];
    const float* emb    = (const float*)d_in[3];
    const float* W_attn = (const float*)d_in[4];
    const float* b_attn = (const float*)d_in[5];
    const float* vvec   = (const float*)d_in[6];
    const float* W_comb = (const float*)d_in[7];
    const float* b_comb = (const float*)d_in[8];
    const float* W_ih   = (const float*)d_in[9];
    const float* W_hh   = (const float*)d_in[10];
    const float* b_ih   = (const float*)d_in[11];
    const float* b_hh   = (const float*)d_in[12];
    const float* W_out  = (const float*)d_in[13];
    const float* b_out  = (const float*)d_in[14];

    float* out = (float*)d_out;
    float* ws = (float*)d_ws;
    float* baseT = ws;                        // 16384
    float* emb_g = ws + 16384;                // 16384
    float* attn  = ws + 32768;                // 262144
    float* part  = ws + 294912;               // 1048576
    float* y     = ws + 1343488;              // 49152
    unsigned short* w2frag = (unsigned short*)(ws + 1392640); // 131072 bf16

    hipLaunchKernelGGL(k1_embed_base, dim3(Bn), dim3(256), 0, stream,
                       ids, hidden, emb, W_attn, b_attn, baseT, emb_g);
    hipLaunchKernelGGL(k1b_w2frag, dim3(256), dim3(64), 0, stream,
                       W_attn, w2frag);
    hipLaunchKernelGGL(k2_scores, dim3(4096), dim3(256), 0, stream,
                       enc, w2frag, vvec, baseT, attn);
    hipLaunchKernelGGL(k3_softmax, dim3(Bn), dim3(1024), 0, stream, attn);
    hipLaunchKernelGGL(k4_ctx_part, dim3(32, Bn), dim3(256), 0, stream,
                       enc, attn, part);
    hipLaunchKernelGGL(k5_ctx_reduce, dim3(Bn), dim3(256), 0, stream, part, y);
    hipLaunchKernelGGL(k6_gru, dim3(Bn), dim3(256), 0, stream,
                       hidden, emb_g, W_comb, b_comb, W_ih, W_hh, b_ih, b_hh,
                       y, out + (size_t)Bn * Vn);
    hipLaunchKernelGGL(k7_logits, dim3((Vn + 63) / 64), dim3(256), 0, stream,
                       W_out, b_out, y, out);
    hipLaunchKernelGGL(k8_logsoftmax, dim3(Bn), dim3(1024), 0, stream, out);
}

// Round 9
// 500.131 us; speedup vs baseline: 1.4372x; 1.3329x over previous
//
#include <hip/hip_runtime.h>
#include <hip/hip_bf16.h>
#include <cstdint>
#include <cstddef>

#define Tn 4096
#define Bn 64
#define Hn 256
#define En 256
#define Vn 50257
#define D2H 512   // 2H
#define K3H 768   // 3H

typedef __attribute__((ext_vector_type(8))) short short8;
typedef __attribute__((ext_vector_type(4))) float f32x4;

__device__ __forceinline__ short bfs(float f)
{
    __hip_bfloat16 h = __float2bfloat16(f);   // RNE
    return *reinterpret_cast<short*>(&h);
}

__device__ __forceinline__ short8 pack8(const float4 x0, const float4 x1)
{
    short8 r;
    r[0] = bfs(x0.x); r[1] = bfs(x0.y); r[2] = bfs(x0.z); r[3] = bfs(x0.w);
    r[4] = bfs(x1.x); r[5] = bfs(x1.y); r[6] = bfs(x1.z); r[7] = bfs(x1.w);
    return r;
}

__device__ __forceinline__ uint2 pack4(const float4 v)
{
    uint2 r;
    r.x = (unsigned)(unsigned short)bfs(v.x) | ((unsigned)(unsigned short)bfs(v.y) << 16);
    r.y = (unsigned)(unsigned short)bfs(v.z) | ((unsigned)(unsigned short)bfs(v.w) << 16);
    return r;
}

__device__ __forceinline__ float bf2f(unsigned short u)
{
    return __uint_as_float(((unsigned)u) << 16);
}

// ---------------------------------------------------------------------------
// ws layout (float offsets):
//   baseB  : [0, 16384)            (64b x 256h)  b_attn + W1 @ h0
//   emb_g  : [16384, 32768)        (64b x 256e)
//   meta   : [32768, 40960)        float2[4096]  (m, l) per (chunk, b)
//   part   : [40960, 2138112)      [4096][512]   ctx partials
//   y      : [2138112, 2187264)    (64b x 768)   [h_new(256) | ctx(512)]
//   w2frag : [2187264, 2252800)    256 KB bf16 W2 fragments
// total ~9.0 MB
// ---------------------------------------------------------------------------

// K1: embedding gather + baseB[b][h] = b_attn[h] + W_attn[h][0:256] . h0[b]
__global__ __launch_bounds__(256) void k1_embed_base(
    const int* __restrict__ ids, const float* __restrict__ hidden,
    const float* __restrict__ emb, const float* __restrict__ W_attn,
    const float* __restrict__ b_attn,
    float* __restrict__ baseB, float* __restrict__ emb_g)
{
    const int b = blockIdx.x, h = threadIdx.x;
    __shared__ float h0[Hn];
    h0[h] = hidden[b * Hn + h];
    __syncthreads();
    float acc = b_attn[h];
    const float* wrow = W_attn + (size_t)h * K3H;
#pragma unroll 8
    for (int k = 0; k < Hn; ++k) acc += wrow[k] * h0[k];
    baseB[b * Hn + h] = acc;               // [b][h]: coalesced for k2f epilogue
    const int id = ids[b];
    emb_g[b * En + h] = emb[(size_t)id * En + h];
}

// K1b: pack W2 = W_attn[:, 256:768] into bf16 MFMA B-fragment layout.
__global__ __launch_bounds__(64) void k1b_w2frag(
    const float* __restrict__ W_attn, unsigned short* __restrict__ w2frag)
{
    const int blk = blockIdx.x;          // nt*16 + kb
    const int nt = blk >> 4, kb = blk & 15;
    const int l = threadIdx.x, lr = l & 15, lg = l >> 4;
    const int h = nt * 16 + lr;
    const float* src = W_attn + (size_t)h * K3H + Hn + kb * 32 + lg * 8;
    float4 x0 = *reinterpret_cast<const float4*>(src);
    float4 x1 = *reinterpret_cast<const float4*>(src + 4);
    reinterpret_cast<short8*>(w2frag)[(size_t)blk * 64 + l] = pack8(x0, x1);
}

// K2F: FUSED scores + local-softmax + context-partial. One block = one
// (t-chunk of 64, b). enc is read ONCE: staged global->reg->bf16->LDS into a
// persistent [64][520] bf16 tile that serves both the MFMA A-fragments (direct
// bf16 ds_read_b128, no repack) and the PV/context accumulation.
// 4 waves = 4 N-slices of 64 h; acc[4][4]; depth-2 reg prefetch with
// bfr-first issue (FIFO) + lgkmcnt-only barrier (glb stays in flight).
__global__ __launch_bounds__(256, 2) void k2f_attn(
    const float* __restrict__ enc, const unsigned short* __restrict__ w2frag,
    const float* __restrict__ vvec, const float* __restrict__ baseB,
    float* __restrict__ part, float2* __restrict__ meta)
{
    const int tid = threadIdx.x;
    const int bx  = blockIdx.x;
    const int b   = bx & 63;
    const int cid = bx >> 6;            // t-chunk id, t = cid*64 .. +63
    const int l = tid & 63;
    const int w = tid >> 6;             // 0..3 = N-slice of 64 h
    const int lr = l & 15, lg = l >> 4;

    __shared__ unsigned short abf[64][520];   // persistent bf16 A tile, 66.5 KB
    __shared__ float red[64][5];
    __shared__ float wts[64];

    f32x4 acc[4][4];
    const f32x4 zero = {0.f, 0.f, 0.f, 0.f};
#pragma unroll
    for (int mi = 0; mi < 4; ++mi)
#pragma unroll
        for (int ni = 0; ni < 4; ++ni) acc[mi][ni] = zero;

    const short8* wf = reinterpret_cast<const short8*>(w2frag);

    // staging: wave w stages rows w*16+u*4+lg (u=0..3), cols lr*4 (16 B f32)
    const float* gbase = enc + ((size_t)(cid * 64 + w * 16 + lg) * Bn + b) * D2H
                       + lr * 4;
    // row-quad stride: 4*Bn*D2H = 131072 floats

#define LOADREG(dst, c) do {                                                  \
    _Pragma("unroll")                                                         \
    for (int u = 0; u < 4; ++u)                                               \
        dst[u] = *reinterpret_cast<const float4*>(                            \
            gbase + (size_t)u * 131072 + (c) * 64);                           \
    } while (0)

#define WRITEC(src, c) do {                                                   \
    _Pragma("unroll")                                                         \
    for (int u = 0; u < 4; ++u)                                               \
        *reinterpret_cast<uint2*>(&abf[w * 16 + u * 4 + lg][(c) * 64 + lr * 4])\
            = pack4(src[u]);                                                  \
    } while (0)

#define COMPUTE_KB(kb, bfr) do {                                              \
    _Pragma("unroll")                                                         \
    for (int mi = 0; mi < 4; ++mi) {                                          \
        short8 a = *reinterpret_cast<const short8*>(                          \
            &abf[mi * 16 + lr][(kb) * 32 + lg * 8]);                          \
        _Pragma("unroll")                                                     \
        for (int ni = 0; ni < 4; ++ni)                                        \
            acc[mi][ni] = __builtin_amdgcn_mfma_f32_16x16x32_bf16(            \
                a, bfr[ni], acc[mi][ni], 0, 0, 0);                            \
    } } while (0)

    float4 st0[4], st1[4];
    // prologue: chunks 0 (write now) and 1 (in flight)
    LOADREG(st0, 0);
    LOADREG(st1, 1);
    WRITEC(st0, 0);                      // compiler waits st0 only (FIFO)
    asm volatile("s_waitcnt lgkmcnt(0)" ::: "memory");
    __builtin_amdgcn_s_barrier();
    __builtin_amdgcn_sched_barrier(0);

#pragma unroll
    for (int kc = 0; kc < 8; ++kc) {
        // B-fragments FIRST: their wait drains only older vmem (chunk kc+1's
        // regs), leaving this iter's prefetch (kc+2) in flight through compute
        short8 bfr0[4], bfr1[4];
#pragma unroll
        for (int ni = 0; ni < 4; ++ni)
            bfr0[ni] = wf[(size_t)(((w * 4 + ni) * 16) + 2 * kc) * 64 + l];
#pragma unroll
        for (int ni = 0; ni < 4; ++ni)
            bfr1[ni] = wf[(size_t)(((w * 4 + ni) * 16) + 2 * kc + 1) * 64 + l];
        __builtin_amdgcn_sched_barrier(0);   // pin: bfr issued before glb
        if (kc < 6) {
            if ((kc & 1) == 0) LOADREG(st0, kc + 2);
            else               LOADREG(st1, kc + 2);
        }
        COMPUTE_KB(2 * kc,     bfr0);
        COMPUTE_KB(2 * kc + 1, bfr1);
        if (kc < 7) {
            if ((kc & 1) == 0) WRITEC(st1, kc + 1);
            else               WRITEC(st0, kc + 1);
        }
        asm volatile("s_waitcnt lgkmcnt(0)" ::: "memory");
        __builtin_amdgcn_s_barrier();
        __builtin_amdgcn_sched_barrier(0);
    }
#undef LOADREG
#undef WRITEC
#undef COMPUTE_KB

    // scores: psum[mi][r] = sum_ni v[h]*tanh(acc + baseB[b][h]); t=mi*16+lg*4+r
    float psum[4][4];
#pragma unroll
    for (int mi = 0; mi < 4; ++mi)
#pragma unroll
        for (int r = 0; r < 4; ++r) psum[mi][r] = 0.f;
#pragma unroll
    for (int ni = 0; ni < 4; ++ni) {
        const int h = w * 64 + ni * 16 + lr;
        const float vh = vvec[h];
        const float bt = baseB[b * Hn + h];
#pragma unroll
        for (int mi = 0; mi < 4; ++mi)
#pragma unroll
            for (int r = 0; r < 4; ++r)
                psum[mi][r] += vh * tanhf(acc[mi][ni][r] + bt);
    }
    // reduce the 16 h-lanes (lr) within each lg group
#pragma unroll
    for (int d = 1; d < 16; d <<= 1)
#pragma unroll
        for (int mi = 0; mi < 4; ++mi)
#pragma unroll
            for (int r = 0; r < 4; ++r)
                psum[mi][r] += __shfl_xor(psum[mi][r], d, 64);
    if (lr == 0) {
#pragma unroll
        for (int mi = 0; mi < 4; ++mi)
#pragma unroll
            for (int r = 0; r < 4; ++r)
                red[mi * 16 + lg * 4 + r][w] = psum[mi][r];
    }
    __syncthreads();

    // wave 0: local softmax over this block's 64 t's; write wts + meta
    if (tid < 64) {
        float s = red[tid][0] + red[tid][1] + red[tid][2] + red[tid][3];
        float m = s;
#pragma unroll
        for (int d = 1; d < 64; d <<= 1) m = fmaxf(m, __shfl_xor(m, d, 64));
        const float e = expf(s - m);
        float lsum = e;
#pragma unroll
        for (int d = 1; d < 64; d <<= 1) lsum += __shfl_xor(lsum, d, 64);
        wts[tid] = e;
        if (tid == 0) meta[bx] = make_float2(m, lsum);
    }
    __syncthreads();

    // context partial from the persistent bf16 tile: ctx[d] = sum_t w_t*enc
    const int d0 = tid * 2;
    float c0 = 0.f, c1 = 0.f;
#pragma unroll 4
    for (int t = 0; t < 64; ++t) {
        const float wt = wts[t];
        const unsigned u = *reinterpret_cast<const unsigned*>(&abf[t][d0]);
        c0 += wt * bf2f((unsigned short)(u & 0xffffu));
        c1 += wt * bf2f((unsigned short)(u >> 16));
    }
    float* pp = part + (size_t)bx * 512 + d0;
    pp[0] = c0; pp[1] = c1;
}

// K5N: cross-chunk softmax combine with rescaling -> ctx into y[b][256:768]
__global__ __launch_bounds__(256) void k5n_combine(
    const float* __restrict__ part, const float2* __restrict__ meta,
    float* __restrict__ y)
{
    const int b = blockIdx.x, tid = threadIdx.x;
    __shared__ float sc[64];
    if (tid < 64) {
        const float2 ml = meta[(size_t)tid * 64 + b];
        float M = ml.x;
#pragma unroll
        for (int d = 1; d < 64; d <<= 1) M = fmaxf(M, __shfl_xor(M, d, 64));
        const float e = expf(ml.x - M);
        float L = e * ml.y;
#pragma unroll
        for (int d = 1; d < 64; d <<= 1) L += __shfl_xor(L, d, 64);
        sc[tid] = e / L;
    }
    __syncthreads();
    const int d0 = tid * 2;
    float c0 = 0.f, c1 = 0.f;
#pragma unroll 4
    for (int c = 0; c < 64; ++c) {
        const float s = sc[c];
        const float2 p = *reinterpret_cast<const float2*>(
            part + ((size_t)c * 64 + b) * 512 + d0);
        c0 += s * p.x; c1 += s * p.y;
    }
    y[(size_t)b * K3H + Hn + d0]     = c0;
    y[(size_t)b * K3H + Hn + d0 + 1] = c1;
}

// K6: combine + GRU
__global__ __launch_bounds__(256) void k6_gru(
    const float* __restrict__ hidden, const float* __restrict__ emb_g,
    const float* __restrict__ W_comb, const float* __restrict__ b_comb,
    const float* __restrict__ W_ih, const float* __restrict__ W_hh,
    const float* __restrict__ b_ih, const float* __restrict__ b_hh,
    float* __restrict__ y, float* __restrict__ out_hidden)
{
    const int b = blockIdx.x, h = threadIdx.x;
    __shared__ float in_[K3H];
    __shared__ float h0[Hn];
    __shared__ float comb[Hn];
    __shared__ float gx[K3H], gh[K3H];
    in_[h]       = y[(size_t)b * K3H + Hn + h];
    in_[256 + h] = y[(size_t)b * K3H + Hn + 256 + h];
    in_[512 + h] = emb_g[b * En + h];
    h0[h] = hidden[b * Hn + h];
    __syncthreads();
    {
        float c = b_comb[h];
        const float* wr = W_comb + (size_t)h * K3H;
#pragma unroll 8
        for (int k = 0; k < K3H; ++k) c += wr[k] * in_[k];
        comb[h] = c;
    }
    __syncthreads();
#pragma unroll
    for (int p = 0; p < 3; ++p) {
        const int g = p * 256 + h;
        float a = b_ih[g], bh = b_hh[g];
        const float* wi = W_ih + (size_t)g * Hn;
        const float* wh = W_hh + (size_t)g * Hn;
#pragma unroll 8
        for (int k = 0; k < Hn; ++k) { a += wi[k] * comb[k]; bh += wh[k] * h0[k]; }
        gx[g] = a; gh[g] = bh;
    }
    __syncthreads();
    const float r = 1.f / (1.f + expf(-(gx[h] + gh[h])));
    const float z = 1.f / (1.f + expf(-(gx[256 + h] + gh[256 + h])));
    const float n = tanhf(gx[512 + h] + r * gh[512 + h]);
    const float hn = (1.f - z) * n + z * h0[h];
    y[(size_t)b * K3H + h] = hn;
    out_hidden[b * Hn + h] = hn;
}

// K7: logits GEMM (64v x 64b tiles)
__global__ __launch_bounds__(256) void k7_logits(
    const float* __restrict__ W_out, const float* __restrict__ b_out,
    const float* __restrict__ y, float* __restrict__ out)
{
    const int vbase = blockIdx.x * 64;
    const int tv = threadIdx.x & 15;
    const int tb = threadIdx.x >> 4;
    __shared__ float lw[64][33];
    __shared__ float ly[32][68];
    float acc[4][4] = {};
    for (int kc = 0; kc < 24; ++kc) {
        __syncthreads();
#pragma unroll
        for (int u = 0; u < 8; ++u) {
            int idx = threadIdx.x + u * 256;
            int r = idx >> 5, c = idx & 31;
            int vv = vbase + r;
            lw[r][c] = (vv < Vn) ? W_out[(size_t)vv * K3H + kc * 32 + c] : 0.f;
        }
#pragma unroll
        for (int u = 0; u < 8; ++u) {
            int idx = threadIdx.x + u * 256;
            int k = idx >> 6, bb = idx & 63;
            ly[k][bb] = y[(size_t)bb * K3H + kc * 32 + k];
        }
        __syncthreads();
        for (int k = 0; k < 32; ++k) {
            float wv[4], yv[4];
#pragma unroll
            for (int i = 0; i < 4; ++i) wv[i] = lw[tv * 4 + i][k];
#pragma unroll
            for (int j = 0; j < 4; ++j) yv[j] = ly[k][tb * 4 + j];
#pragma unroll
            for (int i = 0; i < 4; ++i)
#pragma unroll
                for (int j = 0; j < 4; ++j) acc[i][j] += wv[i] * yv[j];
        }
    }
#pragma unroll
    for (int i = 0; i < 4; ++i) {
        const int vv = vbase + tv * 4 + i;
        if (vv < Vn) {
            const float bo = b_out[vv];
#pragma unroll
            for (int j = 0; j < 4; ++j) {
                const int b = tb * 4 + j;
                out[(size_t)b * Vn + vv] = acc[i][j] + bo;
            }
        }
    }
}

// K8: log_softmax over V per row
__global__ __launch_bounds__(1024) void k8_logsoftmax(float* __restrict__ out)
{
    const int b = blockIdx.x;
    float* row = out + (size_t)b * Vn;
    __shared__ float red[1024];
    float m = -1e30f;
    for (int i = threadIdx.x; i < Vn; i += 1024) m = fmaxf(m, row[i]);
    red[threadIdx.x] = m; __syncthreads();
    for (int s = 512; s > 0; s >>= 1) {
        if (threadIdx.x < s) red[threadIdx.x] = fmaxf(red[threadIdx.x], red[threadIdx.x + s]);
        __syncthreads();
    }
    m = red[0]; __syncthreads();
    float l = 0.f;
    for (int i = threadIdx.x; i < Vn; i += 1024) l += expf(row[i] - m);
    red[threadIdx.x] = l; __syncthreads();
    for (int s = 512; s > 0; s >>= 1) {
        if (threadIdx.x < s) red[threadIdx.x] += red[threadIdx.x + s];
        __syncthreads();
    }
    l = red[0];
    const float off = m + logf(l);
    for (int i = threadIdx.x; i < Vn; i += 1024) row[i] = row[i] - off;
}

extern "C" void kernel_launch(void* const* d_in, const int* in_sizes, int n_in,
                              void* d_out, int out_size, void* d_ws, size_t ws_size,
                              hipStream_t stream)
{
    const int*   ids    = (const int*)d_in[0];
    const float* hidden = (const float*)d_in[1];
    const float* enc    = (const float*)d_in[2];
    const float* emb    = (const float*)d_in[3];
    const float* W_attn = (const float*)d_in[4];
    const float* b_attn = (const float*)d_in[5];
    const float* vvec   = (const float*)d_in[6];
    const float* W_comb = (const float*)d_in[7];
    const float* b_comb = (const float*)d_in[8];
    const float* W_ih   = (const float*)d_in[9];
    const float* W_hh   = (const float*)d_in[10];
    const float* b_ih   = (const float*)d_in[11];
    const float* b_hh   = (const float*)d_in[12];
    const float* W_out  = (const float*)d_in[13];
    const float* b_out  = (const float*)d_in[14];

    float* out = (float*)d_out;
    float* ws = (float*)d_ws;
    float*  baseB = ws;                               // 16384
    float*  emb_g = ws + 16384;                       // 16384
    float2* meta  = (float2*)(ws + 32768);            // 4096 float2
    float*  part  = ws + 40960;                       // 2097152
    float*  y     = ws + 2138112;                     // 49152
    unsigned short* w2frag = (unsigned short*)(ws + 2187264); // 131072 bf16

    hipLaunchKernelGGL(k1_embed_base, dim3(Bn), dim3(256), 0, stream,
                       ids, hidden, emb, W_attn, b_attn, baseB, emb_g);
    hipLaunchKernelGGL(k1b_w2frag, dim3(256), dim3(64), 0, stream,
                       W_attn, w2frag);
    hipLaunchKernelGGL(k2f_attn, dim3(4096), dim3(256), 0, stream,
                       enc, w2frag, vvec, baseB, part, meta);
    hipLaunchKernelGGL(k5n_combine, dim3(Bn), dim3(256), 0, stream,
                       part, meta, y);
    hipLaunchKernelGGL(k6_gru, dim3(Bn), dim3(256), 0, stream,
                       hidden, emb_g, W_comb, b_comb, W_ih, W_hh, b_ih, b_hh,
                       y, out + (size_t)Bn * Vn);
    hipLaunchKernelGGL(k7_logits, dim3((Vn + 63) / 64), dim3(256), 0, stream,
                       W_out, b_out, y, out);
    hipLaunchKernelGGL(k8_logsoftmax, dim3(Bn), dim3(1024), 0, stream, out);
}